// Round 8
// baseline (321.567 us; speedup 1.0000x reference)
//
#include <hip/hip_runtime.h>

// Parametric LIF forward (spike output only).
// x: [B=64, T=64, N=8192] fp32.  out: same shape, values in {0,1}.
// Recurrence per (b,n):  u = last*sig + x[t];  s = (u >= th);
//                        last = (u + lamb*(u-last)) * (1-s)
//
// History: R3-R7 fused variants (pipeline depth, f4, phase-split, slice
// islands) all ~76-81us, 2x off roofline. R8 split compute(u8 spikes->ws) +
// expand(ws->f32 out): sum C+E ~= 82us -- but top-5 cutoff (80us fills) hid
// the C/E decomposition, which decides the next move (read-path vs
// write-path).
// R9: DIAGNOSTIC ROUND (resubmit; last round was an infra failure).
// lif_compute is idempotent -> launch it 4x, expand 1x. Output bit-identical
// (absmax 0). Total time yields 3C = R9_total - R8_total (same fixed
// overhead ~160us, same single E):
//   C~60 (read path broken)  -> total ~405-440 -> restructure the READ next.
//   C~28 (expand is slow)    -> total ~315-335 -> fix the WRITE next (~205 in reach).
//   C~40 (both mediocre)     -> total ~360     -> per-CU request efficiency next.
// If C >= ~80 the compute dispatches also surface in top-5 directly.
// Kernels byte-identical to R8 (passed). Only kernel_launch changed.

#define LIF_B 64
#define LIF_T 64
#define LIF_N 8192
#define NV2 (LIF_N / 2)            // f2 per row = 4096
#define UN 8                       // t-steps per stage
#define NSTAGE (LIF_T / UN)        // 8
#define WS_BYTES ((size_t)LIF_B * LIF_T * LIF_N)   // 32 MiB u8 spikes

typedef float f2 __attribute__((ext_vector_type(2)));
typedef float f4 __attribute__((ext_vector_type(4)));
typedef unsigned char u8;
typedef unsigned int  u32;
typedef u8 uc2 __attribute__((ext_vector_type(2)));

// ---------------- Kernel 1: recurrence, u8 spike emit --------------------
__global__ __launch_bounds__(256) void lif_compute_kernel(
    const f2* __restrict__ x,
    const float* __restrict__ tau_p,
    const float* __restrict__ lamb_p,
    const float* __restrict__ th_p,
    uc2* __restrict__ spk)           // same linear indexing as f2 view of out
{
    const int tid = blockIdx.x * blockDim.x + threadIdx.x;   // 0 .. B*NV2-1
    const int b   = tid >> 12;                               // / NV2
    const int n2  = tid & (NV2 - 1);

    const float sig  = 1.0f / (1.0f + expf(-tau_p[0]));      // 0.5 exact
    const float lamb = lamb_p[0];
    const float th   = th_p[0];

    float lx = 0.0f, ly = 0.0f;
    const size_t base = (size_t)b * LIF_T * NV2 + n2;

    f2 cur[UN], nxt[UN];

#pragma unroll
    for (int i = 0; i < UN; ++i)
        cur[i] = x[base + (size_t)i * NV2];

#pragma unroll
    for (int k = 0; k < NSTAGE; ++k) {
        if (k + 1 < NSTAGE) {
#pragma unroll
            for (int i = 0; i < UN; ++i)
                nxt[i] = x[base + (size_t)((k + 1) * UN + i) * NV2];
        }

#pragma unroll
        for (int i = 0; i < UN; ++i) {
            f2 v = cur[i];
            uc2 sb;
            {
                float u = __fadd_rn(__fmul_rn(lx, sig), v.x);
                bool  c = (u >= th);
                float s = c ? 1.0f : 0.0f;
                lx = __fmul_rn(__fadd_rn(u, __fmul_rn(lamb, __fsub_rn(u, lx))),
                               __fsub_rn(1.0f, s));
                sb.x = c ? (u8)1 : (u8)0;
            }
            {
                float u = __fadd_rn(__fmul_rn(ly, sig), v.y);
                bool  c = (u >= th);
                float s = c ? 1.0f : 0.0f;
                ly = __fmul_rn(__fadd_rn(u, __fmul_rn(lamb, __fsub_rn(u, ly))),
                               __fsub_rn(1.0f, s));
                sb.y = c ? (u8)1 : (u8)0;
            }
            // Plain (cached) store: 2B/lane, stays in L2 -> L3 at kernel end.
            spk[base + (size_t)(k * UN + i) * NV2] = sb;
        }

#pragma unroll
        for (int i = 0; i < UN; ++i)
            cur[i] = nxt[i];
    }
}

// ---------------- Kernel 2: fill-like expander ---------------------------
// 2048 blocks x 256 threads x 16 u32 = 8,388,608 u32 = full tensor.
__global__ __launch_bounds__(256) void lif_expand_kernel(
    const u32* __restrict__ spk,
    f4* __restrict__ out)
{
    const int base = blockIdx.x * (256 * 16) + threadIdx.x;
#pragma unroll
    for (int i = 0; i < 16; ++i) {
        const int idx = base + i * 256;          // lanes adjacent per instr
        const u32 w = spk[idx];
        f4 v;
        v.x = (w & 0x000000ffu) ? 1.0f : 0.0f;
        v.y = (w & 0x0000ff00u) ? 1.0f : 0.0f;
        v.z = (w & 0x00ff0000u) ? 1.0f : 0.0f;
        v.w = (w & 0xff000000u) ? 1.0f : 0.0f;
        __builtin_nontemporal_store(v, &out[idx]);
    }
}

// ---------------- Fallback: proven fused kernel (R2 shape) ---------------
__global__ __launch_bounds__(256, 4) void lif_fused_kernel(
    const f2* __restrict__ x,
    const float* __restrict__ tau_p,
    const float* __restrict__ lamb_p,
    const float* __restrict__ th_p,
    f2* __restrict__ out)
{
    const int tid = blockIdx.x * blockDim.x + threadIdx.x;
    const int b   = tid >> 12;
    const int n2  = tid & (NV2 - 1);

    const float sig  = 1.0f / (1.0f + expf(-tau_p[0]));
    const float lamb = lamb_p[0];
    const float th   = th_p[0];

    float lx = 0.0f, ly = 0.0f;
    const size_t base = (size_t)b * LIF_T * NV2 + n2;

    f2 cur[UN], nxt[UN];
#pragma unroll
    for (int i = 0; i < UN; ++i)
        cur[i] = x[base + (size_t)i * NV2];

#pragma unroll
    for (int k = 0; k < NSTAGE; ++k) {
        if (k + 1 < NSTAGE) {
#pragma unroll
            for (int i = 0; i < UN; ++i)
                nxt[i] = x[base + (size_t)((k + 1) * UN + i) * NV2];
        }
#pragma unroll
        for (int i = 0; i < UN; ++i) {
            f2 v = cur[i];
            f2 sv;
            {
                float u = __fadd_rn(__fmul_rn(lx, sig), v.x);
                float s = (u >= th) ? 1.0f : 0.0f;
                lx = __fmul_rn(__fadd_rn(u, __fmul_rn(lamb, __fsub_rn(u, lx))),
                               __fsub_rn(1.0f, s));
                sv.x = s;
            }
            {
                float u = __fadd_rn(__fmul_rn(ly, sig), v.y);
                float s = (u >= th) ? 1.0f : 0.0f;
                ly = __fmul_rn(__fadd_rn(u, __fmul_rn(lamb, __fsub_rn(u, ly))),
                               __fsub_rn(1.0f, s));
                sv.y = s;
            }
            __builtin_nontemporal_store(sv, &out[base + (size_t)(k * UN + i) * NV2]);
        }
#pragma unroll
        for (int i = 0; i < UN; ++i)
            cur[i] = nxt[i];
    }
}

extern "C" void kernel_launch(void* const* d_in, const int* in_sizes, int n_in,
                              void* d_out, int out_size, void* d_ws, size_t ws_size,
                              hipStream_t stream) {
    (void)in_sizes; (void)n_in; (void)out_size;

    const f2*    x     = (const f2*)d_in[0];
    const float* tau_p = (const float*)d_in[1];
    const float* lamb  = (const float*)d_in[2];
    const float* th    = (const float*)d_in[3];

    if (d_ws != nullptr && ws_size >= WS_BYTES) {
        // DIAGNOSTIC: compute is idempotent; 4 launches -> total time
        // encodes 3C over the R8 baseline. Output unchanged.
        lif_compute_kernel<<<1024, 256, 0, stream>>>(x, tau_p, lamb, th, (uc2*)d_ws);
        lif_compute_kernel<<<1024, 256, 0, stream>>>(x, tau_p, lamb, th, (uc2*)d_ws);
        lif_compute_kernel<<<1024, 256, 0, stream>>>(x, tau_p, lamb, th, (uc2*)d_ws);
        lif_compute_kernel<<<1024, 256, 0, stream>>>(x, tau_p, lamb, th, (uc2*)d_ws);
        lif_expand_kernel<<<2048, 256, 0, stream>>>((const u32*)d_ws, (f4*)d_out);
    } else {
        lif_fused_kernel<<<1024, 256, 0, stream>>>(x, tau_p, lamb, th, (f2*)d_out);
    }
}

// Round 9
// 238.281 us; speedup vs baseline: 1.3495x; 1.3495x over previous
//
#include <hip/hip_runtime.h>

// Parametric LIF forward (spike output only).
// x: [B=64, T=64, N=8192] fp32.  out: same shape, values in {0,1}.
// Recurrence per (b,n):  u = last*sig + x[t];  s = (u >= th);
//                        last = (u + lamb*(u-last)) * (1-s)
//
// History:
//  R3-R7: fused variants (pipeline depth, f4, phase-split, slice islands)
//    ALL ~76-81us -- 2.4 TB/s, 2x off roofline, invariant to structure.
//  R8: split compute(u8->ws, PLAIN stores) + expand(ws->f32, NT stores).
//  R9: 4x-compute diagnostic => C ~= 26.6us (5 TB/s: read path is FINE),
//    E ~= 55-59us (2.3 TB/s for a pure 128MiB write: write path is BROKEN).
//  Attribution: every slow kernel (all fused variants + expand) used
//  __builtin_nontemporal_store; every fast kernel on this chip (runtime
//  fills 6.7 TB/s, R8 compute 5 TB/s) uses PLAIN cached stores. nt bypasses
//  L2 -> loses L2 write-combining/burst aggregation -> ~2.5x write penalty.
//  That one shared instruction explains why five structural theories were
//  all null.
// R10: proven fused R2-shape kernel, ONE change: plain stores (write-back
//  through L2). x and out are both touched exactly once -> no reuse lost to
//  the streaming writes. Arithmetic untouched (*_rn split ops, no FMA) ->
//  bitwise-identical spikes, absmax 0.

#define LIF_B 64
#define LIF_T 64
#define LIF_N 8192
#define NV2 (LIF_N / 2)            // f2 per row = 4096
#define UN 8                       // t-steps per stage
#define NSTAGE (LIF_T / UN)        // 8

typedef float f2 __attribute__((ext_vector_type(2)));

__global__ __launch_bounds__(256, 4) void lif_fwd_kernel(
    const f2* __restrict__ x,
    const float* __restrict__ tau_p,
    const float* __restrict__ lamb_p,
    const float* __restrict__ th_p,
    f2* __restrict__ out)
{
    const int tid = blockIdx.x * blockDim.x + threadIdx.x;   // 0 .. B*NV2-1
    const int b   = tid >> 12;                               // / NV2 (4096)
    const int n2  = tid & (NV2 - 1);

    const float sig  = 1.0f / (1.0f + expf(-tau_p[0]));      // 0.5 exact
    const float lamb = lamb_p[0];
    const float th   = th_p[0];

    float lx = 0.0f, ly = 0.0f;                              // carried state
    const size_t base = (size_t)b * LIF_T * NV2 + n2;

    f2 cur[UN], nxt[UN];

    // Prologue: stage 0 in flight.
#pragma unroll
    for (int i = 0; i < UN; ++i)
        cur[i] = x[base + (size_t)i * NV2];

#pragma unroll
    for (int k = 0; k < NSTAGE; ++k) {
        // 1) Prefetch stage k+1 first.
        if (k + 1 < NSTAGE) {
#pragma unroll
            for (int i = 0; i < UN; ++i)
                nxt[i] = x[base + (size_t)((k + 1) * UN + i) * NV2];
        }

        // 2) Compute + store stage k — PLAIN stores (L2 write-combining).
#pragma unroll
        for (int i = 0; i < UN; ++i) {
            f2 v = cur[i];
            f2 sv;
            {
                float u = __fadd_rn(__fmul_rn(lx, sig), v.x);
                float s = (u >= th) ? 1.0f : 0.0f;
                lx = __fmul_rn(__fadd_rn(u, __fmul_rn(lamb, __fsub_rn(u, lx))),
                               __fsub_rn(1.0f, s));
                sv.x = s;
            }
            {
                float u = __fadd_rn(__fmul_rn(ly, sig), v.y);
                float s = (u >= th) ? 1.0f : 0.0f;
                ly = __fmul_rn(__fadd_rn(u, __fmul_rn(lamb, __fsub_rn(u, ly))),
                               __fsub_rn(1.0f, s));
                sv.y = s;
            }
            out[base + (size_t)(k * UN + i) * NV2] = sv;
        }

        // 3) Rotate (register renames after full unroll).
#pragma unroll
        for (int i = 0; i < UN; ++i)
            cur[i] = nxt[i];
    }
}

extern "C" void kernel_launch(void* const* d_in, const int* in_sizes, int n_in,
                              void* d_out, int out_size, void* d_ws, size_t ws_size,
                              hipStream_t stream) {
    (void)in_sizes; (void)n_in; (void)out_size; (void)d_ws; (void)ws_size;

    const f2*    x     = (const f2*)d_in[0];
    const float* tau_p = (const float*)d_in[1];
    const float* lamb  = (const float*)d_in[2];
    const float* th    = (const float*)d_in[3];
    f2*          out   = (f2*)d_out;

    const int total_threads = LIF_B * NV2;           // 262144
    const int block = 256;
    const int grid  = total_threads / block;         // 1024
    lif_fwd_kernel<<<grid, block, 0, stream>>>(x, tau_p, lamb, th, out);
}